// Round 8
// baseline (1111.825 us; speedup 1.0000x reference)
//
#include <hip/hip_runtime.h>
#include <hip/hip_fp16.h>
#include <math.h>

// Problem: B=16, M=1024, N=1024 fp32; 20 ADMM iterations.
// RHO=1, LAMBD=0.1, ALPHA=0.5 -> threshold = 0.05, scale-const = 0.05.
//
// Fused persistent kernel; V_t in VGPRs, sqrt(R0') in per-block LDS (fp16).
//   X_t = sc_t * softthr(V_t);  Z_t = V_t - X_t
//   R_{t+1} = normalize(sqrt(R0') * sqrt(X_t') * exp(-Z_t/2))
//   V_{t+1} = R_{t+1} + Z_t
// V >= 0 provably holds every iteration, so softthr(x) = fmaxf(x-THR, 0).
//
// R8 diagnosis across R2-R7: the AMDGPU allocator targets the occupancy the
// (compile-time-visible) LDS allows. All prior fused variants used DYNAMIC
// LDS -> compiler assumed LDS=0 -> targeted 8 waves/EU -> 64 VGPRs -> V
// spilled to scratch (594-678 MB warm WRITE). waves_per_eu(4,4) was dropped
// (conflict with __launch_bounds__ macro): VGPR stayed 64.
// Fix: variant A uses STATIC 36 KB LDS (compiler sees 4 blocks/CU ceiling)
// + attribute-only flat_work_group_size/waves_per_eu, no __launch_bounds__.
// Variant B is R5's proven 884-us kernel. Host selects by READING the
// compiled truth: hipFuncGetAttributes(A).localSizeBytes == 0 -> A, else B,
// else the proven multi-kernel fallback.
#define NN 1024
#define NROWS 16384
#define TPB 256           // 4 waves/block
#define WPB 4
#define NIT 20

// A: 4 rows/wave -> 16 rows/block -> 1024 blocks (4/CU), 36 KB static LDS
#define A_RPW 4
#define A_RPB (WPB * A_RPW)
#define A_NGRID (NROWS / A_RPB)   // 1024
// B: 8 rows/wave -> 32 rows/block -> 512 blocks (2/CU), 68 KB dynamic LDS
#define B_RPW 8
#define B_RPB (WPB * B_RPW)
#define B_NGRID (NROWS / B_RPB)   // 512
#define B_LDS_BYTES (32 * NN * 2 + NN * 4)

#define F_KSLOT 8                 // fused colsum spread
// fallback config (proven 1108 us)
#define FB_RPW 2
#define FB_RPB (WPB * FB_RPW)
#define FB_NGRID (NROWS / FB_RPB) // 2048
#define KSLOT 16                  // fallback colsum spread (max layout)

#define MINV 1e-40f
#define THR  0.05f   // ALPHA*LAMBD/RHO
#define SCLC 0.05f   // (1-ALPHA)*LAMBD/RHO
#define EPSL 1e-10f

#define CS_BYTES ((size_t)NIT * KSLOT * NN * sizeof(float))  // max layout
#define NARR 64                   // arrival counters
#define ARR_STRIDE 16             // u32s -> 64 B apart

struct h4 { __half2 a, b; };      // 4 packed fp16

__device__ __forceinline__ float wred_sum(float v) {
#pragma unroll
  for (int o = 32; o > 0; o >>= 1) v += __shfl_xor(v, o, 64);
  return v;
}
__device__ __forceinline__ float softthr_full(float x) {
  return copysignf(fmaxf(fabsf(x) - THR, 0.0f), x);
}

// Two-level grid barrier, generation g = 1,2,3,...  bpa = blocks per counter.
__device__ __forceinline__ void gbar2(unsigned* __restrict__ arr,
                                      unsigned* __restrict__ rel, unsigned g,
                                      unsigned bpa) {
  __syncthreads();
  if (threadIdx.x == 0) {
    __threadfence();  // release my block's cs atomics
    __hip_atomic_fetch_add(&arr[(blockIdx.x & (NARR - 1)) * ARR_STRIDE], 1u,
                           __ATOMIC_RELEASE, __HIP_MEMORY_SCOPE_AGENT);
  }
  if (blockIdx.x == 0) {
    if (threadIdx.x < NARR) {
      const unsigned tgt = bpa * g;
      while (__hip_atomic_load(&arr[threadIdx.x * ARR_STRIDE], __ATOMIC_RELAXED,
                               __HIP_MEMORY_SCOPE_AGENT) < tgt)
        __builtin_amdgcn_s_sleep(1);
    }
    __syncthreads();
    if (threadIdx.x == 0) {
      __threadfence();
      __hip_atomic_store(rel, g, __ATOMIC_RELEASE, __HIP_MEMORY_SCOPE_AGENT);
    }
  } else {
    if (threadIdx.x == 0) {
      while (__hip_atomic_load(rel, __ATOMIC_RELAXED,
                               __HIP_MEMORY_SCOPE_AGENT) < g)
        __builtin_amdgcn_s_sleep(2);
      __threadfence();  // acquire side
    }
    __syncthreads();
  }
}

// Reduce csloc[16] across the 4 waves via s_red (4 KB), then one global
// atomicAdd per column into this block's cs slot.
__device__ __forceinline__ void reduce_push(float* __restrict__ s_red,
                                            float (&csloc)[16],
                                            float* __restrict__ dstbase,
                                            int wv, int lane) {
  __syncthreads();  // prior s_red role (scale broadcast) fully consumed
  if (wv == 0) {
#pragma unroll
    for (int c = 0; c < 4; ++c)
      *(float4*)(&s_red[c * 256 + lane * 4]) = make_float4(
          csloc[c * 4 + 0], csloc[c * 4 + 1], csloc[c * 4 + 2], csloc[c * 4 + 3]);
  }
  __syncthreads();
  if (wv != 0) {
#pragma unroll
    for (int c = 0; c < 4; ++c) {
#pragma unroll
      for (int j = 0; j < 4; ++j)
        atomicAdd(&s_red[c * 256 + lane * 4 + j], csloc[c * 4 + j]);
    }
  }
  __syncthreads();
  const int col = (wv * 64 + lane) * 4;
  const float4 v = *(const float4*)(&s_red[col]);
  atomicAdd(dstbase + col + 0, v.x);
  atomicAdd(dstbase + col + 1, v.y);
  atomicAdd(dstbase + col + 2, v.z);
  atomicAdd(dstbase + col + 3, v.w);
}

// ===================== variant A: static LDS, RPW=4 ========================
// Layout: row = blockIdx.x*16 + wave*4 + rr; lane L covers cols {c*256+L*4+j}.
__attribute__((amdgpu_flat_work_group_size(TPB, TPB), amdgpu_waves_per_eu(4, 4)))
__global__ void k_fa(const float* __restrict__ R0, float* __restrict__ OUT,
                     float* __restrict__ cs, unsigned* __restrict__ arr,
                     unsigned* __restrict__ rel) {
  __shared__ __half sq_h[16 * NN];   // 32 KB  (STATIC: compiler sees 36 KB
  __shared__ float s_red[NN];        //  4 KB   -> 4 blocks/CU ceiling)
  const int lane = threadIdx.x & 63;
  const int wv = threadIdx.x >> 6;
  const int lrow = wv * A_RPW;
  const size_t row0 = (size_t)blockIdx.x * A_RPB + lrow;

  float V[A_RPW][16];   // persistent per-thread state (64 VGPRs)
  float csloc[16];
#pragma unroll
  for (int i = 0; i < 16; ++i) csloc[i] = 0.f;

  // ---- iter 0
#pragma unroll
  for (int rr = 0; rr < A_RPW; ++rr) {
    const size_t base = (row0 + rr) * NN + (size_t)lane * 4;
    float sloc = 0.f;
#pragma unroll
    for (int c = 0; c < 4; ++c) {
      const float4 r4 = *(const float4*)(R0 + base + c * 256);
      const float p0 = (r4.x == 0.f) ? MINV : r4.x;
      const float p1 = (r4.y == 0.f) ? MINV : r4.y;
      const float p2 = (r4.z == 0.f) ? MINV : r4.z;
      const float p3 = (r4.w == 0.f) ? MINV : r4.w;
      V[rr][c * 4 + 0] = p0;
      V[rr][c * 4 + 1] = p1;
      V[rr][c * 4 + 2] = p2;
      V[rr][c * 4 + 3] = p3;
      sloc += (p0 + p1) + (p2 + p3);
      h4 hv;
      hv.a = __floats2half2_rn(sqrtf(p0), sqrtf(p1));
      hv.b = __floats2half2_rn(sqrtf(p2), sqrtf(p3));
      *(h4*)(&sq_h[(lrow + rr) * NN + c * 256 + lane * 4]) = hv;
    }
    const float inv = 1.0f / wred_sum(sloc);
#pragma unroll
    for (int c = 0; c < 4; ++c) {
#pragma unroll
      for (int j = 0; j < 4; ++j) {
        const float rn = V[rr][c * 4 + j] * inv;  // V_1 = R_1 (Z_0 = 0)
        V[rr][c * 4 + j] = rn;
        const float s = fmaxf(rn - THR, 0.f);     // V >= 0
        csloc[c * 4 + j] += s * s;
      }
    }
  }
  reduce_push(s_red, csloc, cs + (size_t)(blockIdx.x & (F_KSLOT - 1)) * NN,
              wv, lane);
  gbar2(arr, rel, 1u, A_NGRID / NARR);

  // ---- iters t=1..19
#pragma unroll 1
  for (int t = 1; t < NIT; ++t) {
    const int last = (t == NIT - 1) ? 1 : 0;
    const float* csP = cs + (size_t)(t - 1) * F_KSLOT * NN;
    float* csN = cs + (size_t)t * F_KSLOT * NN;

    {  // Phase 0: scale -> s_red broadcast
      const int col = threadIdx.x * 4;
      float4 a = make_float4(0.f, 0.f, 0.f, 0.f);
#pragma unroll
      for (int k = 0; k < F_KSLOT; ++k) {
        const float4 v = *(const float4*)(csP + (size_t)k * NN + col);
        a.x += v.x; a.y += v.y; a.z += v.z; a.w += v.w;
      }
      float4 sc4;
      sc4.x = fmaxf(1.0f - SCLC / (sqrtf(a.x) + EPSL), 0.0f);
      sc4.y = fmaxf(1.0f - SCLC / (sqrtf(a.y) + EPSL), 0.0f);
      sc4.z = fmaxf(1.0f - SCLC / (sqrtf(a.z) + EPSL), 0.0f);
      sc4.w = fmaxf(1.0f - SCLC / (sqrtf(a.w) + EPSL), 0.0f);
      *(float4*)(&s_red[col]) = sc4;
    }
    __syncthreads();

#pragma unroll
    for (int i = 0; i < 16; ++i) csloc[i] = 0.f;

#pragma unroll
    for (int rr = 0; rr < A_RPW; ++rr) {
      float u[16];
      float sloc = 0.f;
#pragma unroll
      for (int c = 0; c < 4; ++c) {
        const h4 hv = *(const h4*)(&sq_h[(lrow + rr) * NN + c * 256 + lane * 4]);
        const float2 f01 = __half22float2(hv.a);
        const float2 f23 = __half22float2(hv.b);
        const float sqv[4] = {f01.x, f01.y, f23.x, f23.y};
        const float4 sc4 = *(const float4*)(&s_red[c * 256 + lane * 4]);
        const float scv[4] = {sc4.x, sc4.y, sc4.z, sc4.w};
#pragma unroll
        for (int j = 0; j < 4; ++j) {
          const float vv = V[rr][c * 4 + j];
          const float s = fmaxf(vv - THR, 0.f);   // softthr, V>=0
          const float X = scv[j] * s;
          const float zz = vv - X;                // Z_t
          const float Xm = (X == 0.f) ? MINV : X;
          const float uu = sqv[j] * sqrtf(Xm) * __expf(-0.5f * zz);
          u[c * 4 + j] = uu;
          V[rr][c * 4 + j] = zz;                  // state slot now holds z
          sloc += uu;
        }
      }
      const float inv = 1.0f / wred_sum(sloc);
      if (!last) {
#pragma unroll
        for (int c = 0; c < 4; ++c) {
#pragma unroll
          for (int j = 0; j < 4; ++j) {
            const float nv = u[c * 4 + j] * inv + V[rr][c * 4 + j];  // R+z
            V[rr][c * 4 + j] = nv;               // V_{t+1}
            const float s = fmaxf(nv - THR, 0.f);
            csloc[c * 4 + j] += s * s;
          }
        }
      } else {
        const size_t base = (row0 + rr) * NN + (size_t)lane * 4;
#pragma unroll
        for (int c = 0; c < 4; ++c) {
          *(float4*)(OUT + base + c * 256) =
              make_float4(u[c * 4 + 0] * inv, u[c * 4 + 1] * inv,
                          u[c * 4 + 2] * inv, u[c * 4 + 3] * inv);  // R_20
        }
      }
    }

    if (!last) {
      reduce_push(s_red, csloc,
                  csN + (size_t)(blockIdx.x & (F_KSLOT - 1)) * NN, wv, lane);
      gbar2(arr, rel, (unsigned)(t + 1), A_NGRID / NARR);
    }
  }
}

// ============== variant B: R5's proven 884-us kernel (RPW=8) ===============
__global__ __launch_bounds__(TPB, 2) void k_fb(const float* __restrict__ R0,
                                               float* __restrict__ OUT,
                                               float* __restrict__ cs,
                                               unsigned* __restrict__ arr,
                                               unsigned* __restrict__ rel) {
  extern __shared__ char smem[];
  __half* sq_h = (__half*)smem;                     // [32][1024] fp16, 64 KB
  float* s_red = (float*)(smem + 32 * NN * 2);      // [1024] f32, 4 KB
  const int lane = threadIdx.x & 63;
  const int wv = threadIdx.x >> 6;
  const int lrow = wv * B_RPW;
  const size_t row0 = (size_t)blockIdx.x * B_RPB + lrow;

  float V[B_RPW][16];
  float csloc[16];
#pragma unroll
  for (int i = 0; i < 16; ++i) csloc[i] = 0.f;

#pragma unroll
  for (int rr = 0; rr < B_RPW; ++rr) {
    const size_t base = (row0 + rr) * NN + (size_t)lane * 4;
    float sloc = 0.f;
#pragma unroll
    for (int c = 0; c < 4; ++c) {
      const float4 r4 = *(const float4*)(R0 + base + c * 256);
      const float p0 = (r4.x == 0.f) ? MINV : r4.x;
      const float p1 = (r4.y == 0.f) ? MINV : r4.y;
      const float p2 = (r4.z == 0.f) ? MINV : r4.z;
      const float p3 = (r4.w == 0.f) ? MINV : r4.w;
      V[rr][c * 4 + 0] = p0;
      V[rr][c * 4 + 1] = p1;
      V[rr][c * 4 + 2] = p2;
      V[rr][c * 4 + 3] = p3;
      sloc += (p0 + p1) + (p2 + p3);
      h4 hv;
      hv.a = __floats2half2_rn(sqrtf(p0), sqrtf(p1));
      hv.b = __floats2half2_rn(sqrtf(p2), sqrtf(p3));
      *(h4*)(&sq_h[(lrow + rr) * NN + c * 256 + lane * 4]) = hv;
    }
    const float inv = 1.0f / wred_sum(sloc);
#pragma unroll
    for (int c = 0; c < 4; ++c) {
#pragma unroll
      for (int j = 0; j < 4; ++j) {
        const float rn = V[rr][c * 4 + j] * inv;
        V[rr][c * 4 + j] = rn;
        const float s = fmaxf(rn - THR, 0.f);
        csloc[c * 4 + j] += s * s;
      }
    }
  }
  reduce_push(s_red, csloc, cs + (size_t)(blockIdx.x & (F_KSLOT - 1)) * NN,
              wv, lane);
  gbar2(arr, rel, 1u, B_NGRID / NARR);

#pragma unroll 1
  for (int t = 1; t < NIT; ++t) {
    const int last = (t == NIT - 1) ? 1 : 0;
    const float* csP = cs + (size_t)(t - 1) * F_KSLOT * NN;
    float* csN = cs + (size_t)t * F_KSLOT * NN;
    {
      const int col = threadIdx.x * 4;
      float4 a = make_float4(0.f, 0.f, 0.f, 0.f);
#pragma unroll
      for (int k = 0; k < F_KSLOT; ++k) {
        const float4 v = *(const float4*)(csP + (size_t)k * NN + col);
        a.x += v.x; a.y += v.y; a.z += v.z; a.w += v.w;
      }
      float4 sc4;
      sc4.x = fmaxf(1.0f - SCLC / (sqrtf(a.x) + EPSL), 0.0f);
      sc4.y = fmaxf(1.0f - SCLC / (sqrtf(a.y) + EPSL), 0.0f);
      sc4.z = fmaxf(1.0f - SCLC / (sqrtf(a.z) + EPSL), 0.0f);
      sc4.w = fmaxf(1.0f - SCLC / (sqrtf(a.w) + EPSL), 0.0f);
      *(float4*)(&s_red[col]) = sc4;
    }
    __syncthreads();

#pragma unroll
    for (int i = 0; i < 16; ++i) csloc[i] = 0.f;

#pragma unroll
    for (int rr = 0; rr < B_RPW; ++rr) {
      float u[16];
      float sloc = 0.f;
#pragma unroll
      for (int c = 0; c < 4; ++c) {
        const h4 hv = *(const h4*)(&sq_h[(lrow + rr) * NN + c * 256 + lane * 4]);
        const float2 f01 = __half22float2(hv.a);
        const float2 f23 = __half22float2(hv.b);
        const float sqv[4] = {f01.x, f01.y, f23.x, f23.y};
        const float4 sc4 = *(const float4*)(&s_red[c * 256 + lane * 4]);
        const float scv[4] = {sc4.x, sc4.y, sc4.z, sc4.w};
#pragma unroll
        for (int j = 0; j < 4; ++j) {
          const float vv = V[rr][c * 4 + j];
          const float s = fmaxf(vv - THR, 0.f);
          const float X = scv[j] * s;
          const float zz = vv - X;
          const float Xm = (X == 0.f) ? MINV : X;
          const float uu = sqv[j] * sqrtf(Xm) * __expf(-0.5f * zz);
          u[c * 4 + j] = uu;
          V[rr][c * 4 + j] = zz;
          sloc += uu;
        }
      }
      const float inv = 1.0f / wred_sum(sloc);
      if (!last) {
#pragma unroll
        for (int c = 0; c < 4; ++c) {
#pragma unroll
          for (int j = 0; j < 4; ++j) {
            const float nv = u[c * 4 + j] * inv + V[rr][c * 4 + j];
            V[rr][c * 4 + j] = nv;
            const float s = fmaxf(nv - THR, 0.f);
            csloc[c * 4 + j] += s * s;
          }
        }
      } else {
        const size_t base = (row0 + rr) * NN + (size_t)lane * 4;
#pragma unroll
        for (int c = 0; c < 4; ++c) {
          *(float4*)(OUT + base + c * 256) =
              make_float4(u[c * 4 + 0] * inv, u[c * 4 + 1] * inv,
                          u[c * 4 + 2] * inv, u[c * 4 + 3] * inv);
        }
      }
    }

    if (!last) {
      reduce_push(s_red, csloc,
                  csN + (size_t)(blockIdx.x & (F_KSLOT - 1)) * NN, wv, lane);
      gbar2(arr, rel, (unsigned)(t + 1), B_NGRID / NARR);
    }
  }
}

// ======================= fallback (proven, 1108 µs) ========================
__global__ __launch_bounds__(TPB) void k_start(const float* __restrict__ R0,
                                               float* __restrict__ V,
                                               float* __restrict__ SQ,
                                               float* __restrict__ cs0) {
  __shared__ float s_part[WPB * NN];
  const int lane = threadIdx.x & 63;
  const int wv = threadIdx.x >> 6;
#pragma unroll
  for (int rr = 0; rr < FB_RPW; ++rr) {
    const size_t row = (size_t)blockIdx.x * FB_RPB + wv * FB_RPW + rr;
    const size_t base = row * NN + (size_t)lane * 4;
    float r0v[16];
    float sloc = 0.f;
#pragma unroll
    for (int c = 0; c < 4; ++c) {
      const float4 r4 = *(const float4*)(R0 + base + c * 256);
      r0v[c * 4 + 0] = (r4.x == 0.f) ? MINV : r4.x;
      r0v[c * 4 + 1] = (r4.y == 0.f) ? MINV : r4.y;
      r0v[c * 4 + 2] = (r4.z == 0.f) ? MINV : r4.z;
      r0v[c * 4 + 3] = (r4.w == 0.f) ? MINV : r4.w;
      sloc += (r0v[c * 4 + 0] + r0v[c * 4 + 1]) + (r0v[c * 4 + 2] + r0v[c * 4 + 3]);
      *(float4*)(SQ + base + c * 256) =
          make_float4(sqrtf(r0v[c * 4 + 0]), sqrtf(r0v[c * 4 + 1]),
                      sqrtf(r0v[c * 4 + 2]), sqrtf(r0v[c * 4 + 3]));
    }
    const float inv = 1.0f / wred_sum(sloc);
#pragma unroll
    for (int c = 0; c < 4; ++c) {
      float rn[4], a[4];
#pragma unroll
      for (int j = 0; j < 4; ++j) {
        rn[j] = r0v[c * 4 + j] * inv;
        const float s = softthr_full(rn[j]);
        a[j] = s * s;
      }
      *(float4*)(V + base + c * 256) = make_float4(rn[0], rn[1], rn[2], rn[3]);
      float* sp = &s_part[wv * NN + c * 256 + lane * 4];
      if (rr == 0) {
        *(float4*)sp = make_float4(a[0], a[1], a[2], a[3]);
      } else {
        float4 o = *(float4*)sp;
        *(float4*)sp = make_float4(o.x + a[0], o.y + a[1], o.z + a[2], o.w + a[3]);
      }
    }
  }
  __syncthreads();
  const int col = threadIdx.x * 4;
  const float4 s0 = *(float4*)(&s_part[0 * NN + col]);
  const float4 s1 = *(float4*)(&s_part[1 * NN + col]);
  const float4 s2 = *(float4*)(&s_part[2 * NN + col]);
  const float4 s3 = *(float4*)(&s_part[3 * NN + col]);
  float* dst = cs0 + (size_t)(blockIdx.x & (KSLOT - 1)) * NN + col;
  atomicAdd(dst + 0, (s0.x + s1.x) + (s2.x + s3.x));
  atomicAdd(dst + 1, (s0.y + s1.y) + (s2.y + s3.y));
  atomicAdd(dst + 2, (s0.z + s1.z) + (s2.z + s3.z));
  atomicAdd(dst + 3, (s0.w + s1.w) + (s2.w + s3.w));
}

__global__ __launch_bounds__(TPB) void k_ab(float* __restrict__ V,
                                            const float* __restrict__ SQ,
                                            const float* __restrict__ csPrev,
                                            float* __restrict__ csNext,
                                            int last) {
  __shared__ float s_scale[NN];
  __shared__ float s_part[WPB * NN];
  const int lane = threadIdx.x & 63;
  const int wv = threadIdx.x >> 6;
  {
    const int col = threadIdx.x * 4;
    float4 a = make_float4(0.f, 0.f, 0.f, 0.f);
#pragma unroll
    for (int k = 0; k < KSLOT; ++k) {
      const float4 v = *(const float4*)(csPrev + (size_t)k * NN + col);
      a.x += v.x; a.y += v.y; a.z += v.z; a.w += v.w;
    }
    s_scale[col + 0] = fmaxf(1.0f - SCLC / (sqrtf(a.x) + EPSL), 0.0f);
    s_scale[col + 1] = fmaxf(1.0f - SCLC / (sqrtf(a.y) + EPSL), 0.0f);
    s_scale[col + 2] = fmaxf(1.0f - SCLC / (sqrtf(a.z) + EPSL), 0.0f);
    s_scale[col + 3] = fmaxf(1.0f - SCLC / (sqrtf(a.w) + EPSL), 0.0f);
  }
  __syncthreads();

#pragma unroll
  for (int rr = 0; rr < FB_RPW; ++rr) {
    const size_t row = (size_t)blockIdx.x * FB_RPB + wv * FB_RPW + rr;
    const size_t base = row * NN + (size_t)lane * 4;
    float u[16], z[16];
    float sloc = 0.f;
#pragma unroll
    for (int c = 0; c < 4; ++c) {
      const float4 vv4 = *(const float4*)(V + base + c * 256);
      const float4 sq4 = *(const float4*)(SQ + base + c * 256);
      const float4 sc4 = *(const float4*)(&s_scale[c * 256 + lane * 4]);
      const float vv[4] = {vv4.x, vv4.y, vv4.z, vv4.w};
      const float sq[4] = {sq4.x, sq4.y, sq4.z, sq4.w};
      const float sc[4] = {sc4.x, sc4.y, sc4.z, sc4.w};
#pragma unroll
      for (int j = 0; j < 4; ++j) {
        const float s = softthr_full(vv[j]);
        const float X = sc[j] * s;
        const float zz = vv[j] - X;
        z[c * 4 + j] = zz;
        const float Xm = (X == 0.f) ? MINV : X;
        const float uu = sq[j] * sqrtf(Xm) * __expf(-0.5f * zz);
        u[c * 4 + j] = uu;
        sloc += uu;
      }
    }
    const float inv = 1.0f / wred_sum(sloc);
#pragma unroll
    for (int c = 0; c < 4; ++c) {
      float outv[4];
#pragma unroll
      for (int j = 0; j < 4; ++j) {
        const float rn = u[c * 4 + j] * inv;
        outv[j] = last ? rn : (rn + z[c * 4 + j]);
      }
      *(float4*)(V + base + c * 256) =
          make_float4(outv[0], outv[1], outv[2], outv[3]);
      if (!last) {
        float a[4];
#pragma unroll
        for (int j = 0; j < 4; ++j) {
          const float s = softthr_full(outv[j]);
          a[j] = s * s;
        }
        float* sp = &s_part[wv * NN + c * 256 + lane * 4];
        if (rr == 0) {
          *(float4*)sp = make_float4(a[0], a[1], a[2], a[3]);
        } else {
          float4 o = *(float4*)sp;
          *(float4*)sp =
              make_float4(o.x + a[0], o.y + a[1], o.z + a[2], o.w + a[3]);
        }
      }
    }
  }
  if (!last) {
    __syncthreads();
    const int col = threadIdx.x * 4;
    const float4 s0 = *(float4*)(&s_part[0 * NN + col]);
    const float4 s1 = *(float4*)(&s_part[1 * NN + col]);
    const float4 s2 = *(float4*)(&s_part[2 * NN + col]);
    const float4 s3 = *(float4*)(&s_part[3 * NN + col]);
    float* dst = csNext + (size_t)(blockIdx.x & (KSLOT - 1)) * NN + col;
    atomicAdd(dst + 0, (s0.x + s1.x) + (s2.x + s3.x));
    atomicAdd(dst + 1, (s0.y + s1.y) + (s2.y + s3.y));
    atomicAdd(dst + 2, (s0.z + s1.z) + (s2.z + s3.z));
    atomicAdd(dst + 3, (s0.w + s1.w) + (s2.w + s3.w));
  }
}

extern "C" void kernel_launch(void* const* d_in, const int* in_sizes, int n_in,
                              void* d_out, int out_size, void* d_ws, size_t ws_size,
                              hipStream_t stream) {
  (void)in_sizes; (void)n_in; (void)out_size; (void)ws_size;
  const float* R0 = (const float*)d_in[0];
  float* OUT = (float*)d_out;
  float* SQ = (float*)d_ws;   // 64 MB: used by fallback only
  float* cs = (float*)((char*)d_ws + (size_t)NROWS * NN * sizeof(float));
  unsigned* arr = (unsigned*)((char*)cs + CS_BYTES);       // counters
  unsigned* rel = arr + NARR * ARR_STRIDE + 64;            // own cacheline

  // Select by reading the COMPILED truth: A only if it has zero scratch
  // (no spill) and verified co-residency; else B (proven 884 us, gated);
  // else multi-kernel fallback.
  static int mode = -1;
  if (mode < 0) {
    mode = 0;
    int dev = 0, ncu = 0;
    if (hipGetDevice(&dev) == hipSuccess &&
        hipDeviceGetAttribute(&ncu, hipDeviceAttributeMultiprocessorCount,
                              dev) == hipSuccess) {
      hipFuncAttributes fa{};
      int maxb = 0;
      if (hipFuncGetAttributes(&fa, reinterpret_cast<const void*>(k_fa)) ==
              hipSuccess &&
          fa.localSizeBytes == 0 &&
          hipOccupancyMaxActiveBlocksPerMultiprocessor(&maxb, k_fa, TPB, 0) ==
              hipSuccess &&
          (long)maxb * (long)ncu >= (long)A_NGRID) {
        mode = 1;
      } else if (hipFuncSetAttribute(
                     reinterpret_cast<const void*>(k_fb),
                     hipFuncAttributeMaxDynamicSharedMemorySize,
                     B_LDS_BYTES) == hipSuccess &&
                 hipOccupancyMaxActiveBlocksPerMultiprocessor(
                     &maxb, k_fb, TPB, B_LDS_BYTES) == hipSuccess &&
                 (long)maxb * (long)ncu >= (long)B_NGRID) {
        mode = 2;
      }
    }
  }

  // zero cs slices + arrival counters + release word
  hipMemsetAsync(cs, 0, CS_BYTES + 8192, stream);
  if (mode == 1) {
    k_fa<<<A_NGRID, TPB, 0, stream>>>(R0, OUT, cs, arr, rel);
  } else if (mode == 2) {
    k_fb<<<B_NGRID, TPB, B_LDS_BYTES, stream>>>(R0, OUT, cs, arr, rel);
  } else {
    k_start<<<FB_NGRID, TPB, 0, stream>>>(R0, OUT, SQ, cs);
    for (int it = 1; it < NIT; ++it) {
      k_ab<<<FB_NGRID, TPB, 0, stream>>>(OUT, SQ,
                                         cs + (size_t)(it - 1) * KSLOT * NN,
                                         cs + (size_t)it * KSLOT * NN,
                                         (it == NIT - 1) ? 1 : 0);
    }
  }
}

// Round 9
// 1110.654 us; speedup vs baseline: 1.0011x; 1.0011x over previous
//
#include <hip/hip_runtime.h>
#include <hip/hip_fp16.h>
#include <math.h>

// Problem: B=16, M=1024, N=1024 fp32; 20 ADMM iterations.
// RHO=1, LAMBD=0.1, ALPHA=0.5 -> threshold = 0.05, scale-const = 0.05.
//
// Fused persistent kernel; V_t in VGPRs, sqrt(R0') in per-block LDS (fp16).
//   X_t = sc_t * softthr(V_t);  Z_t = V_t - X_t
//   R_{t+1} = normalize(sqrt(R0') * sqrt(X_t') * exp(-Z_t/2))
//   V_{t+1} = R_{t+1} + Z_t
// V >= 0 provably holds every iteration, so softthr(x) = fmaxf(x-THR, 0).
//
// R9 strategy: 7 rounds show the AMDGPU allocator always targets the
// occupancy it computes feasible (usually 8 waves/EU -> 64 VGPRs) and
// every attempt to force a bigger budget spilled V to scratch. So ALIGN
// with it: variant C shrinks state to fit 64 regs at 8 waves/EU.
//   RPW=2 -> 2048 blocks; V[2][16]=32 regs; peak live ~60.
//   LDS = 16KB fp16 sq + 4KB s_red = 20KB = 160KB/8 blocks exactly.
//   colsum regs (csq) only live after u dies -> no overlap with peak.
// Gate: C iff compiled localSizeBytes<=64 AND occupancy>=2048; else B
// (R5's proven 822us kernel); else the proven multi-kernel fallback.
#define NN 1024
#define NROWS 16384
#define TPB 256           // 4 waves/block
#define WPB 4
#define NIT 20

// C: 2 rows/wave -> 8 rows/block -> 2048 blocks (8/CU), 20 KB static LDS
#define C_RPW 2
#define C_RPB (WPB * C_RPW)
#define C_NGRID (NROWS / C_RPB)   // 2048
// B: 8 rows/wave -> 32 rows/block -> 512 blocks (2/CU), 68 KB dynamic LDS
#define B_RPW 8
#define B_RPB (WPB * B_RPW)
#define B_NGRID (NROWS / B_RPB)   // 512
#define B_LDS_BYTES (32 * NN * 2 + NN * 4)

#define F_KSLOT 8                 // fused colsum spread
// fallback config (proven 1108 us)
#define FB_RPW 2
#define FB_RPB (WPB * FB_RPW)
#define FB_NGRID (NROWS / FB_RPB) // 2048
#define KSLOT 16                  // fallback colsum spread (max layout)

#define MINV 1e-40f
#define THR  0.05f   // ALPHA*LAMBD/RHO
#define SCLC 0.05f   // (1-ALPHA)*LAMBD/RHO
#define EPSL 1e-10f

#define CS_BYTES ((size_t)NIT * KSLOT * NN * sizeof(float))  // max layout
#define NARR 64                   // arrival counters
#define ARR_STRIDE 16             // u32s -> 64 B apart

struct h4 { __half2 a, b; };      // 4 packed fp16

__device__ __forceinline__ float wred_sum(float v) {
#pragma unroll
  for (int o = 32; o > 0; o >>= 1) v += __shfl_xor(v, o, 64);
  return v;
}
__device__ __forceinline__ float softthr_full(float x) {
  return copysignf(fmaxf(fabsf(x) - THR, 0.0f), x);
}

// Two-level grid barrier, generation g = 1,2,3,...  bpa = blocks per counter.
__device__ __forceinline__ void gbar2(unsigned* __restrict__ arr,
                                      unsigned* __restrict__ rel, unsigned g,
                                      unsigned bpa) {
  __syncthreads();
  if (threadIdx.x == 0) {
    __threadfence();  // release my block's cs atomics
    __hip_atomic_fetch_add(&arr[(blockIdx.x & (NARR - 1)) * ARR_STRIDE], 1u,
                           __ATOMIC_RELEASE, __HIP_MEMORY_SCOPE_AGENT);
  }
  if (blockIdx.x == 0) {
    if (threadIdx.x < NARR) {
      const unsigned tgt = bpa * g;
      while (__hip_atomic_load(&arr[threadIdx.x * ARR_STRIDE], __ATOMIC_RELAXED,
                               __HIP_MEMORY_SCOPE_AGENT) < tgt)
        __builtin_amdgcn_s_sleep(1);
    }
    __syncthreads();
    if (threadIdx.x == 0) {
      __threadfence();
      __hip_atomic_store(rel, g, __ATOMIC_RELEASE, __HIP_MEMORY_SCOPE_AGENT);
    }
  } else {
    if (threadIdx.x == 0) {
      while (__hip_atomic_load(rel, __ATOMIC_RELAXED,
                               __HIP_MEMORY_SCOPE_AGENT) < g)
        __builtin_amdgcn_s_sleep(2);
      __threadfence();  // acquire side
    }
    __syncthreads();
  }
}

// Reduce csq[16] across the 4 waves via s_red (4 KB), then one global
// atomicAdd per column into this block's cs slot.
__device__ __forceinline__ void reduce_push(float* __restrict__ s_red,
                                            float (&csq)[16],
                                            float* __restrict__ dstbase,
                                            int wv, int lane) {
  __syncthreads();  // prior s_red role (scale broadcast) fully consumed
  if (wv == 0) {
#pragma unroll
    for (int c = 0; c < 4; ++c)
      *(float4*)(&s_red[c * 256 + lane * 4]) = make_float4(
          csq[c * 4 + 0], csq[c * 4 + 1], csq[c * 4 + 2], csq[c * 4 + 3]);
  }
  __syncthreads();
  if (wv != 0) {
#pragma unroll
    for (int c = 0; c < 4; ++c) {
#pragma unroll
      for (int j = 0; j < 4; ++j)
        atomicAdd(&s_red[c * 256 + lane * 4 + j], csq[c * 4 + j]);
    }
  }
  __syncthreads();
  const int col = (wv * 64 + lane) * 4;
  const float4 v = *(const float4*)(&s_red[col]);
  atomicAdd(dstbase + col + 0, v.x);
  atomicAdd(dstbase + col + 1, v.y);
  atomicAdd(dstbase + col + 2, v.z);
  atomicAdd(dstbase + col + 3, v.w);
}

// ============ variant C: 64-VGPR / 20KB-LDS / 8 blocks-per-CU =============
// Layout: row = blockIdx.x*8 + wave*2 + rr; lane L covers cols {c*256+L*4+j}.
__global__ __launch_bounds__(TPB) void k_fc(const float* __restrict__ R0,
                                            float* __restrict__ OUT,
                                            float* __restrict__ cs,
                                            unsigned* __restrict__ arr,
                                            unsigned* __restrict__ rel) {
  __shared__ __half sq_h[C_RPB * NN];  // 16 KB (static: 20 KB total -> the
  __shared__ float s_red[NN];          //  4 KB  compiler sees 8 blocks/CU)
  const int lane = threadIdx.x & 63;
  const int wv = threadIdx.x >> 6;
  const int lrow = wv * C_RPW;
  const size_t row0 = (size_t)blockIdx.x * C_RPB + lrow;

  float V[C_RPW][16];   // persistent per-thread state (32 VGPRs)

  // ---- iter 0: V_1 = R0'/rowsum(R0'); sq_h = fp16(sqrt(R0'));
  {
    float csq[16];
#pragma unroll
    for (int i = 0; i < 16; ++i) csq[i] = 0.f;
#pragma unroll
    for (int rr = 0; rr < C_RPW; ++rr) {
      const size_t base = (row0 + rr) * NN + (size_t)lane * 4;
      float sloc = 0.f;
#pragma unroll
      for (int c = 0; c < 4; ++c) {
        const float4 r4 = *(const float4*)(R0 + base + c * 256);
        const float p0 = (r4.x == 0.f) ? MINV : r4.x;
        const float p1 = (r4.y == 0.f) ? MINV : r4.y;
        const float p2 = (r4.z == 0.f) ? MINV : r4.z;
        const float p3 = (r4.w == 0.f) ? MINV : r4.w;
        V[rr][c * 4 + 0] = p0;
        V[rr][c * 4 + 1] = p1;
        V[rr][c * 4 + 2] = p2;
        V[rr][c * 4 + 3] = p3;
        sloc += (p0 + p1) + (p2 + p3);
        h4 hv;
        hv.a = __floats2half2_rn(sqrtf(p0), sqrtf(p1));
        hv.b = __floats2half2_rn(sqrtf(p2), sqrtf(p3));
        *(h4*)(&sq_h[(lrow + rr) * NN + c * 256 + lane * 4]) = hv;
      }
      const float inv = 1.0f / wred_sum(sloc);
#pragma unroll
      for (int c = 0; c < 4; ++c) {
#pragma unroll
        for (int j = 0; j < 4; ++j) {
          const float rn = V[rr][c * 4 + j] * inv;  // V_1 = R_1 (Z_0 = 0)
          V[rr][c * 4 + j] = rn;
          const float s = fmaxf(rn - THR, 0.f);     // V >= 0
          csq[c * 4 + j] += s * s;
        }
      }
    }
    reduce_push(s_red, csq, cs + (size_t)(blockIdx.x & (F_KSLOT - 1)) * NN,
                wv, lane);
  }
  gbar2(arr, rel, 1u, C_NGRID / NARR);

  // ---- iters t=1..19
#pragma unroll 1
  for (int t = 1; t < NIT; ++t) {
    const int last = (t == NIT - 1) ? 1 : 0;
    const float* csP = cs + (size_t)(t - 1) * F_KSLOT * NN;
    float* csN = cs + (size_t)t * F_KSLOT * NN;

    {  // Phase 0: scale -> s_red broadcast
      const int col = threadIdx.x * 4;
      float4 a = make_float4(0.f, 0.f, 0.f, 0.f);
#pragma unroll
      for (int k = 0; k < F_KSLOT; ++k) {
        const float4 v = *(const float4*)(csP + (size_t)k * NN + col);
        a.x += v.x; a.y += v.y; a.z += v.z; a.w += v.w;
      }
      float4 sc4;
      sc4.x = fmaxf(1.0f - SCLC / (sqrtf(a.x) + EPSL), 0.0f);
      sc4.y = fmaxf(1.0f - SCLC / (sqrtf(a.y) + EPSL), 0.0f);
      sc4.z = fmaxf(1.0f - SCLC / (sqrtf(a.z) + EPSL), 0.0f);
      sc4.w = fmaxf(1.0f - SCLC / (sqrtf(a.w) + EPSL), 0.0f);
      *(float4*)(&s_red[col]) = sc4;
    }
    __syncthreads();

#pragma unroll
    for (int rr = 0; rr < C_RPW; ++rr) {
      float u[16];
      float sloc = 0.f;
#pragma unroll
      for (int c = 0; c < 4; ++c) {
        const h4 hv = *(const h4*)(&sq_h[(lrow + rr) * NN + c * 256 + lane * 4]);
        const float2 f01 = __half22float2(hv.a);
        const float2 f23 = __half22float2(hv.b);
        const float sqv[4] = {f01.x, f01.y, f23.x, f23.y};
        const float4 sc4 = *(const float4*)(&s_red[c * 256 + lane * 4]);
        const float scv[4] = {sc4.x, sc4.y, sc4.z, sc4.w};
#pragma unroll
        for (int j = 0; j < 4; ++j) {
          const float vv = V[rr][c * 4 + j];
          const float s = fmaxf(vv - THR, 0.f);   // softthr, V>=0
          const float X = scv[j] * s;             // X_t (never stored)
          const float zz = vv - X;                // Z_t
          const float Xm = (X == 0.f) ? MINV : X;
          const float uu = sqv[j] * sqrtf(Xm) * __expf(-0.5f * zz);
          u[c * 4 + j] = uu;
          V[rr][c * 4 + j] = zz;                  // state slot now holds z
          sloc += uu;
        }
      }
      const float inv = 1.0f / wred_sum(sloc);
      if (!last) {
#pragma unroll
        for (int i = 0; i < 16; ++i)
          V[rr][i] = u[i] * inv + V[rr][i];       // V_{t+1} = R + z
      } else {
        const size_t base = (row0 + rr) * NN + (size_t)lane * 4;
#pragma unroll
        for (int c = 0; c < 4; ++c) {
          *(float4*)(OUT + base + c * 256) =
              make_float4(u[c * 4 + 0] * inv, u[c * 4 + 1] * inv,
                          u[c * 4 + 2] * inv, u[c * 4 + 3] * inv);  // R_20
        }
      }
    }

    if (!last) {
      // colsum of softthr(V_{t+1})^2 — u is dead here, so csq doesn't
      // overlap the register peak.
      float csq[16];
#pragma unroll
      for (int i = 0; i < 16; ++i) {
        const float s0 = fmaxf(V[0][i] - THR, 0.f);
        const float s1 = fmaxf(V[1][i] - THR, 0.f);
        csq[i] = s0 * s0 + s1 * s1;
      }
      reduce_push(s_red, csq,
                  csN + (size_t)(blockIdx.x & (F_KSLOT - 1)) * NN, wv, lane);
      gbar2(arr, rel, (unsigned)(t + 1), C_NGRID / NARR);
    }
  }
}

// ============== variant B: R5's proven kernel (RPW=8, 822 µs) ==============
__global__ __launch_bounds__(TPB, 2) void k_fb(const float* __restrict__ R0,
                                               float* __restrict__ OUT,
                                               float* __restrict__ cs,
                                               unsigned* __restrict__ arr,
                                               unsigned* __restrict__ rel) {
  extern __shared__ char smem[];
  __half* sq_h = (__half*)smem;                     // [32][1024] fp16, 64 KB
  float* s_red = (float*)(smem + 32 * NN * 2);      // [1024] f32, 4 KB
  const int lane = threadIdx.x & 63;
  const int wv = threadIdx.x >> 6;
  const int lrow = wv * B_RPW;
  const size_t row0 = (size_t)blockIdx.x * B_RPB + lrow;

  float V[B_RPW][16];
  float csq[16];
#pragma unroll
  for (int i = 0; i < 16; ++i) csq[i] = 0.f;

#pragma unroll
  for (int rr = 0; rr < B_RPW; ++rr) {
    const size_t base = (row0 + rr) * NN + (size_t)lane * 4;
    float sloc = 0.f;
#pragma unroll
    for (int c = 0; c < 4; ++c) {
      const float4 r4 = *(const float4*)(R0 + base + c * 256);
      const float p0 = (r4.x == 0.f) ? MINV : r4.x;
      const float p1 = (r4.y == 0.f) ? MINV : r4.y;
      const float p2 = (r4.z == 0.f) ? MINV : r4.z;
      const float p3 = (r4.w == 0.f) ? MINV : r4.w;
      V[rr][c * 4 + 0] = p0;
      V[rr][c * 4 + 1] = p1;
      V[rr][c * 4 + 2] = p2;
      V[rr][c * 4 + 3] = p3;
      sloc += (p0 + p1) + (p2 + p3);
      h4 hv;
      hv.a = __floats2half2_rn(sqrtf(p0), sqrtf(p1));
      hv.b = __floats2half2_rn(sqrtf(p2), sqrtf(p3));
      *(h4*)(&sq_h[(lrow + rr) * NN + c * 256 + lane * 4]) = hv;
    }
    const float inv = 1.0f / wred_sum(sloc);
#pragma unroll
    for (int c = 0; c < 4; ++c) {
#pragma unroll
      for (int j = 0; j < 4; ++j) {
        const float rn = V[rr][c * 4 + j] * inv;
        V[rr][c * 4 + j] = rn;
        const float s = fmaxf(rn - THR, 0.f);
        csq[c * 4 + j] += s * s;
      }
    }
  }
  reduce_push(s_red, csq, cs + (size_t)(blockIdx.x & (F_KSLOT - 1)) * NN,
              wv, lane);
  gbar2(arr, rel, 1u, B_NGRID / NARR);

#pragma unroll 1
  for (int t = 1; t < NIT; ++t) {
    const int last = (t == NIT - 1) ? 1 : 0;
    const float* csP = cs + (size_t)(t - 1) * F_KSLOT * NN;
    float* csN = cs + (size_t)t * F_KSLOT * NN;
    {
      const int col = threadIdx.x * 4;
      float4 a = make_float4(0.f, 0.f, 0.f, 0.f);
#pragma unroll
      for (int k = 0; k < F_KSLOT; ++k) {
        const float4 v = *(const float4*)(csP + (size_t)k * NN + col);
        a.x += v.x; a.y += v.y; a.z += v.z; a.w += v.w;
      }
      float4 sc4;
      sc4.x = fmaxf(1.0f - SCLC / (sqrtf(a.x) + EPSL), 0.0f);
      sc4.y = fmaxf(1.0f - SCLC / (sqrtf(a.y) + EPSL), 0.0f);
      sc4.z = fmaxf(1.0f - SCLC / (sqrtf(a.z) + EPSL), 0.0f);
      sc4.w = fmaxf(1.0f - SCLC / (sqrtf(a.w) + EPSL), 0.0f);
      *(float4*)(&s_red[col]) = sc4;
    }
    __syncthreads();

#pragma unroll
    for (int i = 0; i < 16; ++i) csq[i] = 0.f;

#pragma unroll
    for (int rr = 0; rr < B_RPW; ++rr) {
      float u[16];
      float sloc = 0.f;
#pragma unroll
      for (int c = 0; c < 4; ++c) {
        const h4 hv = *(const h4*)(&sq_h[(lrow + rr) * NN + c * 256 + lane * 4]);
        const float2 f01 = __half22float2(hv.a);
        const float2 f23 = __half22float2(hv.b);
        const float sqv[4] = {f01.x, f01.y, f23.x, f23.y};
        const float4 sc4 = *(const float4*)(&s_red[c * 256 + lane * 4]);
        const float scv[4] = {sc4.x, sc4.y, sc4.z, sc4.w};
#pragma unroll
        for (int j = 0; j < 4; ++j) {
          const float vv = V[rr][c * 4 + j];
          const float s = fmaxf(vv - THR, 0.f);
          const float X = scv[j] * s;
          const float zz = vv - X;
          const float Xm = (X == 0.f) ? MINV : X;
          const float uu = sqv[j] * sqrtf(Xm) * __expf(-0.5f * zz);
          u[c * 4 + j] = uu;
          V[rr][c * 4 + j] = zz;
          sloc += uu;
        }
      }
      const float inv = 1.0f / wred_sum(sloc);
      if (!last) {
#pragma unroll
        for (int c = 0; c < 4; ++c) {
#pragma unroll
          for (int j = 0; j < 4; ++j) {
            const float nv = u[c * 4 + j] * inv + V[rr][c * 4 + j];
            V[rr][c * 4 + j] = nv;
            const float s = fmaxf(nv - THR, 0.f);
            csq[c * 4 + j] += s * s;
          }
        }
      } else {
        const size_t base = (row0 + rr) * NN + (size_t)lane * 4;
#pragma unroll
        for (int c = 0; c < 4; ++c) {
          *(float4*)(OUT + base + c * 256) =
              make_float4(u[c * 4 + 0] * inv, u[c * 4 + 1] * inv,
                          u[c * 4 + 2] * inv, u[c * 4 + 3] * inv);
        }
      }
    }

    if (!last) {
      reduce_push(s_red, csq,
                  csN + (size_t)(blockIdx.x & (F_KSLOT - 1)) * NN, wv, lane);
      gbar2(arr, rel, (unsigned)(t + 1), B_NGRID / NARR);
    }
  }
}

// ======================= fallback (proven, 1108 µs) ========================
__global__ __launch_bounds__(TPB) void k_start(const float* __restrict__ R0,
                                               float* __restrict__ V,
                                               float* __restrict__ SQ,
                                               float* __restrict__ cs0) {
  __shared__ float s_part[WPB * NN];
  const int lane = threadIdx.x & 63;
  const int wv = threadIdx.x >> 6;
#pragma unroll
  for (int rr = 0; rr < FB_RPW; ++rr) {
    const size_t row = (size_t)blockIdx.x * FB_RPB + wv * FB_RPW + rr;
    const size_t base = row * NN + (size_t)lane * 4;
    float r0v[16];
    float sloc = 0.f;
#pragma unroll
    for (int c = 0; c < 4; ++c) {
      const float4 r4 = *(const float4*)(R0 + base + c * 256);
      r0v[c * 4 + 0] = (r4.x == 0.f) ? MINV : r4.x;
      r0v[c * 4 + 1] = (r4.y == 0.f) ? MINV : r4.y;
      r0v[c * 4 + 2] = (r4.z == 0.f) ? MINV : r4.z;
      r0v[c * 4 + 3] = (r4.w == 0.f) ? MINV : r4.w;
      sloc += (r0v[c * 4 + 0] + r0v[c * 4 + 1]) + (r0v[c * 4 + 2] + r0v[c * 4 + 3]);
      *(float4*)(SQ + base + c * 256) =
          make_float4(sqrtf(r0v[c * 4 + 0]), sqrtf(r0v[c * 4 + 1]),
                      sqrtf(r0v[c * 4 + 2]), sqrtf(r0v[c * 4 + 3]));
    }
    const float inv = 1.0f / wred_sum(sloc);
#pragma unroll
    for (int c = 0; c < 4; ++c) {
      float rn[4], a[4];
#pragma unroll
      for (int j = 0; j < 4; ++j) {
        rn[j] = r0v[c * 4 + j] * inv;
        const float s = softthr_full(rn[j]);
        a[j] = s * s;
      }
      *(float4*)(V + base + c * 256) = make_float4(rn[0], rn[1], rn[2], rn[3]);
      float* sp = &s_part[wv * NN + c * 256 + lane * 4];
      if (rr == 0) {
        *(float4*)sp = make_float4(a[0], a[1], a[2], a[3]);
      } else {
        float4 o = *(float4*)sp;
        *(float4*)sp = make_float4(o.x + a[0], o.y + a[1], o.z + a[2], o.w + a[3]);
      }
    }
  }
  __syncthreads();
  const int col = threadIdx.x * 4;
  const float4 s0 = *(float4*)(&s_part[0 * NN + col]);
  const float4 s1 = *(float4*)(&s_part[1 * NN + col]);
  const float4 s2 = *(float4*)(&s_part[2 * NN + col]);
  const float4 s3 = *(float4*)(&s_part[3 * NN + col]);
  float* dst = cs0 + (size_t)(blockIdx.x & (KSLOT - 1)) * NN + col;
  atomicAdd(dst + 0, (s0.x + s1.x) + (s2.x + s3.x));
  atomicAdd(dst + 1, (s0.y + s1.y) + (s2.y + s3.y));
  atomicAdd(dst + 2, (s0.z + s1.z) + (s2.z + s3.z));
  atomicAdd(dst + 3, (s0.w + s1.w) + (s2.w + s3.w));
}

__global__ __launch_bounds__(TPB) void k_ab(float* __restrict__ V,
                                            const float* __restrict__ SQ,
                                            const float* __restrict__ csPrev,
                                            float* __restrict__ csNext,
                                            int last) {
  __shared__ float s_scale[NN];
  __shared__ float s_part[WPB * NN];
  const int lane = threadIdx.x & 63;
  const int wv = threadIdx.x >> 6;
  {
    const int col = threadIdx.x * 4;
    float4 a = make_float4(0.f, 0.f, 0.f, 0.f);
#pragma unroll
    for (int k = 0; k < KSLOT; ++k) {
      const float4 v = *(const float4*)(csPrev + (size_t)k * NN + col);
      a.x += v.x; a.y += v.y; a.z += v.z; a.w += v.w;
    }
    s_scale[col + 0] = fmaxf(1.0f - SCLC / (sqrtf(a.x) + EPSL), 0.0f);
    s_scale[col + 1] = fmaxf(1.0f - SCLC / (sqrtf(a.y) + EPSL), 0.0f);
    s_scale[col + 2] = fmaxf(1.0f - SCLC / (sqrtf(a.z) + EPSL), 0.0f);
    s_scale[col + 3] = fmaxf(1.0f - SCLC / (sqrtf(a.w) + EPSL), 0.0f);
  }
  __syncthreads();

#pragma unroll
  for (int rr = 0; rr < FB_RPW; ++rr) {
    const size_t row = (size_t)blockIdx.x * FB_RPB + wv * FB_RPW + rr;
    const size_t base = row * NN + (size_t)lane * 4;
    float u[16], z[16];
    float sloc = 0.f;
#pragma unroll
    for (int c = 0; c < 4; ++c) {
      const float4 vv4 = *(const float4*)(V + base + c * 256);
      const float4 sq4 = *(const float4*)(SQ + base + c * 256);
      const float4 sc4 = *(const float4*)(&s_scale[c * 256 + lane * 4]);
      const float vv[4] = {vv4.x, vv4.y, vv4.z, vv4.w};
      const float sq[4] = {sq4.x, sq4.y, sq4.z, sq4.w};
      const float sc[4] = {sc4.x, sc4.y, sc4.z, sc4.w};
#pragma unroll
      for (int j = 0; j < 4; ++j) {
        const float s = softthr_full(vv[j]);
        const float X = sc[j] * s;
        const float zz = vv[j] - X;
        z[c * 4 + j] = zz;
        const float Xm = (X == 0.f) ? MINV : X;
        const float uu = sq[j] * sqrtf(Xm) * __expf(-0.5f * zz);
        u[c * 4 + j] = uu;
        sloc += uu;
      }
    }
    const float inv = 1.0f / wred_sum(sloc);
#pragma unroll
    for (int c = 0; c < 4; ++c) {
      float outv[4];
#pragma unroll
      for (int j = 0; j < 4; ++j) {
        const float rn = u[c * 4 + j] * inv;
        outv[j] = last ? rn : (rn + z[c * 4 + j]);
      }
      *(float4*)(V + base + c * 256) =
          make_float4(outv[0], outv[1], outv[2], outv[3]);
      if (!last) {
        float a[4];
#pragma unroll
        for (int j = 0; j < 4; ++j) {
          const float s = softthr_full(outv[j]);
          a[j] = s * s;
        }
        float* sp = &s_part[wv * NN + c * 256 + lane * 4];
        if (rr == 0) {
          *(float4*)sp = make_float4(a[0], a[1], a[2], a[3]);
        } else {
          float4 o = *(float4*)sp;
          *(float4*)sp =
              make_float4(o.x + a[0], o.y + a[1], o.z + a[2], o.w + a[3]);
        }
      }
    }
  }
  if (!last) {
    __syncthreads();
    const int col = threadIdx.x * 4;
    const float4 s0 = *(float4*)(&s_part[0 * NN + col]);
    const float4 s1 = *(float4*)(&s_part[1 * NN + col]);
    const float4 s2 = *(float4*)(&s_part[2 * NN + col]);
    const float4 s3 = *(float4*)(&s_part[3 * NN + col]);
    float* dst = csNext + (size_t)(blockIdx.x & (KSLOT - 1)) * NN + col;
    atomicAdd(dst + 0, (s0.x + s1.x) + (s2.x + s3.x));
    atomicAdd(dst + 1, (s0.y + s1.y) + (s2.y + s3.y));
    atomicAdd(dst + 2, (s0.z + s1.z) + (s2.z + s3.z));
    atomicAdd(dst + 3, (s0.w + s1.w) + (s2.w + s3.w));
  }
}

extern "C" void kernel_launch(void* const* d_in, const int* in_sizes, int n_in,
                              void* d_out, int out_size, void* d_ws, size_t ws_size,
                              hipStream_t stream) {
  (void)in_sizes; (void)n_in; (void)out_size; (void)ws_size;
  const float* R0 = (const float*)d_in[0];
  float* OUT = (float*)d_out;
  float* SQ = (float*)d_ws;   // 64 MB: used by fallback only
  float* cs = (float*)((char*)d_ws + (size_t)NROWS * NN * sizeof(float));
  unsigned* arr = (unsigned*)((char*)cs + CS_BYTES);       // counters
  unsigned* rel = arr + NARR * ARR_STRIDE + 64;            // own cacheline

  // Select by reading the COMPILED truth.
  //  C: needs <=64B scratch (no meaningful spill) AND 2048-block residency.
  //  B: proven 822-us kernel, occupancy-gated.
  //  else: proven multi-kernel fallback.
  static int mode = -1;
  if (mode < 0) {
    mode = 0;
    int dev = 0, ncu = 0;
    if (hipGetDevice(&dev) == hipSuccess &&
        hipDeviceGetAttribute(&ncu, hipDeviceAttributeMultiprocessorCount,
                              dev) == hipSuccess) {
      hipFuncAttributes fc{};
      int maxb = 0;
      if (hipFuncGetAttributes(&fc, reinterpret_cast<const void*>(k_fc)) ==
              hipSuccess &&
          fc.localSizeBytes <= 64 &&
          hipOccupancyMaxActiveBlocksPerMultiprocessor(&maxb, k_fc, TPB, 0) ==
              hipSuccess &&
          (long)maxb * (long)ncu >= (long)C_NGRID) {
        mode = 3;
      } else if (hipFuncSetAttribute(
                     reinterpret_cast<const void*>(k_fb),
                     hipFuncAttributeMaxDynamicSharedMemorySize,
                     B_LDS_BYTES) == hipSuccess &&
                 hipOccupancyMaxActiveBlocksPerMultiprocessor(
                     &maxb, k_fb, TPB, B_LDS_BYTES) == hipSuccess &&
                 (long)maxb * (long)ncu >= (long)B_NGRID) {
        mode = 2;
      }
    }
  }

  // zero cs slices + arrival counters + release word
  hipMemsetAsync(cs, 0, CS_BYTES + 8192, stream);
  if (mode == 3) {
    k_fc<<<C_NGRID, TPB, 0, stream>>>(R0, OUT, cs, arr, rel);
  } else if (mode == 2) {
    k_fb<<<B_NGRID, TPB, B_LDS_BYTES, stream>>>(R0, OUT, cs, arr, rel);
  } else {
    k_start<<<FB_NGRID, TPB, 0, stream>>>(R0, OUT, SQ, cs);
    for (int it = 1; it < NIT; ++it) {
      k_ab<<<FB_NGRID, TPB, 0, stream>>>(OUT, SQ,
                                         cs + (size_t)(it - 1) * KSLOT * NN,
                                         cs + (size_t)it * KSLOT * NN,
                                         (it == NIT - 1) ? 1 : 0);
    }
  }
}

// Round 10
// 1108.702 us; speedup vs baseline: 1.0028x; 1.0018x over previous
//
#include <hip/hip_runtime.h>
#include <hip/hip_fp16.h>
#include <math.h>

// Problem: B=16, M=1024, N=1024 fp32; 20 ADMM iterations.
// RHO=1, LAMBD=0.1, ALPHA=0.5 -> threshold = 0.05, scale-const = 0.05.
//
// Fused persistent kernel; V_t in VGPRs, sqrt(R0') in per-block LDS (fp16).
//   X_t = sc_t * softthr(V_t);  Z_t = V_t - X_t
//   R_{t+1} = normalize(sqrt(R0') * sqrt(X_t') * exp(-Z_t/2))
//   V_{t+1} = R_{t+1} + Z_t
// V >= 0 provably holds every iteration, so softthr(x) = fmaxf(x-THR, 0).
//
// R10: R9's variant C spilled (peak live V32+u16+temps ~= 62-66 > the
// allocator's 64-reg target at the 8-blocks/CU LDS ceiling) -> gate sent us
// to B (802us, 2 waves/SIMD, latency-stalled). Fix: TWO-PASS RECOMPUTE in
// C's inner loop -- pass 1 computes u only into the rowsum (all temps
// chunk-local), pass 2 recomputes u after inv is known and updates V in
// place. u[16] never spans wred_sum -> peak live ~46-50. An empty
// asm("":"+v") on pass-2's vv blocks CSE from resurrecting the live u's.
// iter-0 csq moved after its row loop for the same reason. Spill gate
// relaxed to <=256B (tiny spill at 8 waves/CU is harmless).
#define NN 1024
#define NROWS 16384
#define TPB 256           // 4 waves/block
#define WPB 4
#define NIT 20

// C: 2 rows/wave -> 8 rows/block -> 2048 blocks (8/CU), 20 KB static LDS
#define C_RPW 2
#define C_RPB (WPB * C_RPW)
#define C_NGRID (NROWS / C_RPB)   // 2048
// B: 8 rows/wave -> 32 rows/block -> 512 blocks (2/CU), 68 KB dynamic LDS
#define B_RPW 8
#define B_RPB (WPB * B_RPW)
#define B_NGRID (NROWS / B_RPB)   // 512
#define B_LDS_BYTES (32 * NN * 2 + NN * 4)

#define F_KSLOT 8                 // fused colsum spread
// fallback config (proven 1108 us)
#define FB_RPW 2
#define FB_RPB (WPB * FB_RPW)
#define FB_NGRID (NROWS / FB_RPB) // 2048
#define KSLOT 16                  // fallback colsum spread (max layout)

#define MINV 1e-40f
#define THR  0.05f   // ALPHA*LAMBD/RHO
#define SCLC 0.05f   // (1-ALPHA)*LAMBD/RHO
#define EPSL 1e-10f

#define CS_BYTES ((size_t)NIT * KSLOT * NN * sizeof(float))  // max layout
#define NARR 64                   // arrival counters
#define ARR_STRIDE 16             // u32s -> 64 B apart

struct h4 { __half2 a, b; };      // 4 packed fp16

__device__ __forceinline__ float wred_sum(float v) {
#pragma unroll
  for (int o = 32; o > 0; o >>= 1) v += __shfl_xor(v, o, 64);
  return v;
}
__device__ __forceinline__ float softthr_full(float x) {
  return copysignf(fmaxf(fabsf(x) - THR, 0.0f), x);
}

// Two-level grid barrier, generation g = 1,2,3,...  bpa = blocks per counter.
__device__ __forceinline__ void gbar2(unsigned* __restrict__ arr,
                                      unsigned* __restrict__ rel, unsigned g,
                                      unsigned bpa) {
  __syncthreads();
  if (threadIdx.x == 0) {
    __threadfence();  // release my block's cs atomics
    __hip_atomic_fetch_add(&arr[(blockIdx.x & (NARR - 1)) * ARR_STRIDE], 1u,
                           __ATOMIC_RELEASE, __HIP_MEMORY_SCOPE_AGENT);
  }
  if (blockIdx.x == 0) {
    if (threadIdx.x < NARR) {
      const unsigned tgt = bpa * g;
      while (__hip_atomic_load(&arr[threadIdx.x * ARR_STRIDE], __ATOMIC_RELAXED,
                               __HIP_MEMORY_SCOPE_AGENT) < tgt)
        __builtin_amdgcn_s_sleep(1);
    }
    __syncthreads();
    if (threadIdx.x == 0) {
      __threadfence();
      __hip_atomic_store(rel, g, __ATOMIC_RELEASE, __HIP_MEMORY_SCOPE_AGENT);
    }
  } else {
    if (threadIdx.x == 0) {
      while (__hip_atomic_load(rel, __ATOMIC_RELAXED,
                               __HIP_MEMORY_SCOPE_AGENT) < g)
        __builtin_amdgcn_s_sleep(2);
      __threadfence();  // acquire side
    }
    __syncthreads();
  }
}

// Reduce csq[16] across the 4 waves via s_red (4 KB), then one global
// atomicAdd per column into this block's cs slot.
__device__ __forceinline__ void reduce_push(float* __restrict__ s_red,
                                            float (&csq)[16],
                                            float* __restrict__ dstbase,
                                            int wv, int lane) {
  __syncthreads();  // prior s_red role (scale broadcast) fully consumed
  if (wv == 0) {
#pragma unroll
    for (int c = 0; c < 4; ++c)
      *(float4*)(&s_red[c * 256 + lane * 4]) = make_float4(
          csq[c * 4 + 0], csq[c * 4 + 1], csq[c * 4 + 2], csq[c * 4 + 3]);
  }
  __syncthreads();
  if (wv != 0) {
#pragma unroll
    for (int c = 0; c < 4; ++c) {
#pragma unroll
      for (int j = 0; j < 4; ++j)
        atomicAdd(&s_red[c * 256 + lane * 4 + j], csq[c * 4 + j]);
    }
  }
  __syncthreads();
  const int col = (wv * 64 + lane) * 4;
  const float4 v = *(const float4*)(&s_red[col]);
  atomicAdd(dstbase + col + 0, v.x);
  atomicAdd(dstbase + col + 1, v.y);
  atomicAdd(dstbase + col + 2, v.z);
  atomicAdd(dstbase + col + 3, v.w);
}

// ============ variant C: 64-VGPR / 20KB-LDS / 8 blocks-per-CU =============
// Layout: row = blockIdx.x*8 + wave*2 + rr; lane L covers cols {c*256+L*4+j}.
__global__ __launch_bounds__(TPB) void k_fc(const float* __restrict__ R0,
                                            float* __restrict__ OUT,
                                            float* __restrict__ cs,
                                            unsigned* __restrict__ arr,
                                            unsigned* __restrict__ rel) {
  __shared__ __half sq_h[C_RPB * NN];  // 16 KB (static: 20 KB total -> the
  __shared__ float s_red[NN];          //  4 KB  compiler sees 8 blocks/CU)
  const int lane = threadIdx.x & 63;
  const int wv = threadIdx.x >> 6;
  const int lrow = wv * C_RPW;
  const size_t row0 = (size_t)blockIdx.x * C_RPB + lrow;

  float V[C_RPW][16];   // persistent per-thread state (32 VGPRs)

  // ---- iter 0: V_1 = R0'/rowsum(R0'); sq_h = fp16(sqrt(R0')).
#pragma unroll
  for (int rr = 0; rr < C_RPW; ++rr) {
    const size_t base = (row0 + rr) * NN + (size_t)lane * 4;
    float sloc = 0.f;
#pragma unroll
    for (int c = 0; c < 4; ++c) {
      const float4 r4 = *(const float4*)(R0 + base + c * 256);
      const float p0 = (r4.x == 0.f) ? MINV : r4.x;
      const float p1 = (r4.y == 0.f) ? MINV : r4.y;
      const float p2 = (r4.z == 0.f) ? MINV : r4.z;
      const float p3 = (r4.w == 0.f) ? MINV : r4.w;
      V[rr][c * 4 + 0] = p0;
      V[rr][c * 4 + 1] = p1;
      V[rr][c * 4 + 2] = p2;
      V[rr][c * 4 + 3] = p3;
      sloc += (p0 + p1) + (p2 + p3);
      h4 hv;
      hv.a = __floats2half2_rn(sqrtf(p0), sqrtf(p1));
      hv.b = __floats2half2_rn(sqrtf(p2), sqrtf(p3));
      *(h4*)(&sq_h[(lrow + rr) * NN + c * 256 + lane * 4]) = hv;
    }
    const float inv = 1.0f / wred_sum(sloc);
#pragma unroll
    for (int i = 0; i < 16; ++i) V[rr][i] *= inv;  // V_1 = R_1 (Z_0 = 0)
  }
  {  // csq AFTER the row loop: no overlap with iter-0 temps
    float csq[16];
#pragma unroll
    for (int i = 0; i < 16; ++i) {
      const float s0 = fmaxf(V[0][i] - THR, 0.f);
      const float s1 = fmaxf(V[1][i] - THR, 0.f);
      csq[i] = s0 * s0 + s1 * s1;
    }
    reduce_push(s_red, csq, cs + (size_t)(blockIdx.x & (F_KSLOT - 1)) * NN,
                wv, lane);
  }
  gbar2(arr, rel, 1u, C_NGRID / NARR);

  // ---- iters t=1..19
#pragma unroll 1
  for (int t = 1; t < NIT; ++t) {
    const int last = (t == NIT - 1) ? 1 : 0;
    const float* csP = cs + (size_t)(t - 1) * F_KSLOT * NN;
    float* csN = cs + (size_t)t * F_KSLOT * NN;

    {  // Phase 0: scale -> s_red broadcast
      const int col = threadIdx.x * 4;
      float4 a = make_float4(0.f, 0.f, 0.f, 0.f);
#pragma unroll
      for (int k = 0; k < F_KSLOT; ++k) {
        const float4 v = *(const float4*)(csP + (size_t)k * NN + col);
        a.x += v.x; a.y += v.y; a.z += v.z; a.w += v.w;
      }
      float4 sc4;
      sc4.x = fmaxf(1.0f - SCLC / (sqrtf(a.x) + EPSL), 0.0f);
      sc4.y = fmaxf(1.0f - SCLC / (sqrtf(a.y) + EPSL), 0.0f);
      sc4.z = fmaxf(1.0f - SCLC / (sqrtf(a.z) + EPSL), 0.0f);
      sc4.w = fmaxf(1.0f - SCLC / (sqrtf(a.w) + EPSL), 0.0f);
      *(float4*)(&s_red[col]) = sc4;
    }
    __syncthreads();

#pragma unroll
    for (int rr = 0; rr < C_RPW; ++rr) {
      // ---- pass 1: rowsum only. V untouched; all temps chunk-local.
      float sloc = 0.f;
#pragma unroll
      for (int c = 0; c < 4; ++c) {
        const h4 hv = *(const h4*)(&sq_h[(lrow + rr) * NN + c * 256 + lane * 4]);
        const float2 f01 = __half22float2(hv.a);
        const float2 f23 = __half22float2(hv.b);
        const float sqv[4] = {f01.x, f01.y, f23.x, f23.y};
        const float4 sc4 = *(const float4*)(&s_red[c * 256 + lane * 4]);
        const float scv[4] = {sc4.x, sc4.y, sc4.z, sc4.w};
#pragma unroll
        for (int j = 0; j < 4; ++j) {
          const float vv = V[rr][c * 4 + j];
          const float s = fmaxf(vv - THR, 0.f);   // softthr, V>=0
          const float X = scv[j] * s;
          const float zz = vv - X;
          const float Xm = (X == 0.f) ? MINV : X;
          sloc += sqv[j] * sqrtf(Xm) * __expf(-0.5f * zz);
        }
      }
      const float inv = 1.0f / wred_sum(sloc);

      // ---- pass 2: recompute u with inv known; update V in place.
      // asm("":"+v") on vv blocks CSE with pass 1 (would re-inflate
      // liveness across wred_sum).
#pragma unroll
      for (int c = 0; c < 4; ++c) {
        const h4 hv = *(const h4*)(&sq_h[(lrow + rr) * NN + c * 256 + lane * 4]);
        const float2 f01 = __half22float2(hv.a);
        const float2 f23 = __half22float2(hv.b);
        const float sqv[4] = {f01.x, f01.y, f23.x, f23.y};
        const float4 sc4 = *(const float4*)(&s_red[c * 256 + lane * 4]);
        const float scv[4] = {sc4.x, sc4.y, sc4.z, sc4.w};
        float outv[4];
#pragma unroll
        for (int j = 0; j < 4; ++j) {
          float vv = V[rr][c * 4 + j];
          asm volatile("" : "+v"(vv));            // opacify: no CSE w/ pass 1
          const float s = fmaxf(vv - THR, 0.f);
          const float X = scv[j] * s;
          const float zz = vv - X;                // Z_t
          const float Xm = (X == 0.f) ? MINV : X;
          const float uu = sqv[j] * sqrtf(Xm) * __expf(-0.5f * zz);
          const float rn = uu * inv;              // R_{t+1}
          if (!last) {
            V[rr][c * 4 + j] = rn + zz;           // V_{t+1}
          } else {
            outv[j] = rn;
          }
        }
        if (last) {
          const size_t base = (row0 + rr) * NN + (size_t)lane * 4;
          *(float4*)(OUT + base + c * 256) =
              make_float4(outv[0], outv[1], outv[2], outv[3]);  // R_20
        }
      }
    }

    if (!last) {
      // colsum of softthr(V_{t+1})^2 — after rows, u/temps dead.
      float csq[16];
#pragma unroll
      for (int i = 0; i < 16; ++i) {
        const float s0 = fmaxf(V[0][i] - THR, 0.f);
        const float s1 = fmaxf(V[1][i] - THR, 0.f);
        csq[i] = s0 * s0 + s1 * s1;
      }
      reduce_push(s_red, csq,
                  csN + (size_t)(blockIdx.x & (F_KSLOT - 1)) * NN, wv, lane);
      gbar2(arr, rel, (unsigned)(t + 1), C_NGRID / NARR);
    }
  }
}

// ============== variant B: R5's proven kernel (RPW=8, ~802 µs) =============
__global__ __launch_bounds__(TPB, 2) void k_fb(const float* __restrict__ R0,
                                               float* __restrict__ OUT,
                                               float* __restrict__ cs,
                                               unsigned* __restrict__ arr,
                                               unsigned* __restrict__ rel) {
  extern __shared__ char smem[];
  __half* sq_h = (__half*)smem;                     // [32][1024] fp16, 64 KB
  float* s_red = (float*)(smem + 32 * NN * 2);      // [1024] f32, 4 KB
  const int lane = threadIdx.x & 63;
  const int wv = threadIdx.x >> 6;
  const int lrow = wv * B_RPW;
  const size_t row0 = (size_t)blockIdx.x * B_RPB + lrow;

  float V[B_RPW][16];
  float csq[16];
#pragma unroll
  for (int i = 0; i < 16; ++i) csq[i] = 0.f;

#pragma unroll
  for (int rr = 0; rr < B_RPW; ++rr) {
    const size_t base = (row0 + rr) * NN + (size_t)lane * 4;
    float sloc = 0.f;
#pragma unroll
    for (int c = 0; c < 4; ++c) {
      const float4 r4 = *(const float4*)(R0 + base + c * 256);
      const float p0 = (r4.x == 0.f) ? MINV : r4.x;
      const float p1 = (r4.y == 0.f) ? MINV : r4.y;
      const float p2 = (r4.z == 0.f) ? MINV : r4.z;
      const float p3 = (r4.w == 0.f) ? MINV : r4.w;
      V[rr][c * 4 + 0] = p0;
      V[rr][c * 4 + 1] = p1;
      V[rr][c * 4 + 2] = p2;
      V[rr][c * 4 + 3] = p3;
      sloc += (p0 + p1) + (p2 + p3);
      h4 hv;
      hv.a = __floats2half2_rn(sqrtf(p0), sqrtf(p1));
      hv.b = __floats2half2_rn(sqrtf(p2), sqrtf(p3));
      *(h4*)(&sq_h[(lrow + rr) * NN + c * 256 + lane * 4]) = hv;
    }
    const float inv = 1.0f / wred_sum(sloc);
#pragma unroll
    for (int c = 0; c < 4; ++c) {
#pragma unroll
      for (int j = 0; j < 4; ++j) {
        const float rn = V[rr][c * 4 + j] * inv;
        V[rr][c * 4 + j] = rn;
        const float s = fmaxf(rn - THR, 0.f);
        csq[c * 4 + j] += s * s;
      }
    }
  }
  reduce_push(s_red, csq, cs + (size_t)(blockIdx.x & (F_KSLOT - 1)) * NN,
              wv, lane);
  gbar2(arr, rel, 1u, B_NGRID / NARR);

#pragma unroll 1
  for (int t = 1; t < NIT; ++t) {
    const int last = (t == NIT - 1) ? 1 : 0;
    const float* csP = cs + (size_t)(t - 1) * F_KSLOT * NN;
    float* csN = cs + (size_t)t * F_KSLOT * NN;
    {
      const int col = threadIdx.x * 4;
      float4 a = make_float4(0.f, 0.f, 0.f, 0.f);
#pragma unroll
      for (int k = 0; k < F_KSLOT; ++k) {
        const float4 v = *(const float4*)(csP + (size_t)k * NN + col);
        a.x += v.x; a.y += v.y; a.z += v.z; a.w += v.w;
      }
      float4 sc4;
      sc4.x = fmaxf(1.0f - SCLC / (sqrtf(a.x) + EPSL), 0.0f);
      sc4.y = fmaxf(1.0f - SCLC / (sqrtf(a.y) + EPSL), 0.0f);
      sc4.z = fmaxf(1.0f - SCLC / (sqrtf(a.z) + EPSL), 0.0f);
      sc4.w = fmaxf(1.0f - SCLC / (sqrtf(a.w) + EPSL), 0.0f);
      *(float4*)(&s_red[col]) = sc4;
    }
    __syncthreads();

#pragma unroll
    for (int i = 0; i < 16; ++i) csq[i] = 0.f;

#pragma unroll
    for (int rr = 0; rr < B_RPW; ++rr) {
      float u[16];
      float sloc = 0.f;
#pragma unroll
      for (int c = 0; c < 4; ++c) {
        const h4 hv = *(const h4*)(&sq_h[(lrow + rr) * NN + c * 256 + lane * 4]);
        const float2 f01 = __half22float2(hv.a);
        const float2 f23 = __half22float2(hv.b);
        const float sqv[4] = {f01.x, f01.y, f23.x, f23.y};
        const float4 sc4 = *(const float4*)(&s_red[c * 256 + lane * 4]);
        const float scv[4] = {sc4.x, sc4.y, sc4.z, sc4.w};
#pragma unroll
        for (int j = 0; j < 4; ++j) {
          const float vv = V[rr][c * 4 + j];
          const float s = fmaxf(vv - THR, 0.f);
          const float X = scv[j] * s;
          const float zz = vv - X;
          const float Xm = (X == 0.f) ? MINV : X;
          const float uu = sqv[j] * sqrtf(Xm) * __expf(-0.5f * zz);
          u[c * 4 + j] = uu;
          V[rr][c * 4 + j] = zz;
          sloc += uu;
        }
      }
      const float inv = 1.0f / wred_sum(sloc);
      if (!last) {
#pragma unroll
        for (int c = 0; c < 4; ++c) {
#pragma unroll
          for (int j = 0; j < 4; ++j) {
            const float nv = u[c * 4 + j] * inv + V[rr][c * 4 + j];
            V[rr][c * 4 + j] = nv;
            const float s = fmaxf(nv - THR, 0.f);
            csq[c * 4 + j] += s * s;
          }
        }
      } else {
        const size_t base = (row0 + rr) * NN + (size_t)lane * 4;
#pragma unroll
        for (int c = 0; c < 4; ++c) {
          *(float4*)(OUT + base + c * 256) =
              make_float4(u[c * 4 + 0] * inv, u[c * 4 + 1] * inv,
                          u[c * 4 + 2] * inv, u[c * 4 + 3] * inv);
        }
      }
    }

    if (!last) {
      reduce_push(s_red, csq,
                  csN + (size_t)(blockIdx.x & (F_KSLOT - 1)) * NN, wv, lane);
      gbar2(arr, rel, (unsigned)(t + 1), B_NGRID / NARR);
    }
  }
}

// ======================= fallback (proven, 1108 µs) ========================
__global__ __launch_bounds__(TPB) void k_start(const float* __restrict__ R0,
                                               float* __restrict__ V,
                                               float* __restrict__ SQ,
                                               float* __restrict__ cs0) {
  __shared__ float s_part[WPB * NN];
  const int lane = threadIdx.x & 63;
  const int wv = threadIdx.x >> 6;
#pragma unroll
  for (int rr = 0; rr < FB_RPW; ++rr) {
    const size_t row = (size_t)blockIdx.x * FB_RPB + wv * FB_RPW + rr;
    const size_t base = row * NN + (size_t)lane * 4;
    float r0v[16];
    float sloc = 0.f;
#pragma unroll
    for (int c = 0; c < 4; ++c) {
      const float4 r4 = *(const float4*)(R0 + base + c * 256);
      r0v[c * 4 + 0] = (r4.x == 0.f) ? MINV : r4.x;
      r0v[c * 4 + 1] = (r4.y == 0.f) ? MINV : r4.y;
      r0v[c * 4 + 2] = (r4.z == 0.f) ? MINV : r4.z;
      r0v[c * 4 + 3] = (r4.w == 0.f) ? MINV : r4.w;
      sloc += (r0v[c * 4 + 0] + r0v[c * 4 + 1]) + (r0v[c * 4 + 2] + r0v[c * 4 + 3]);
      *(float4*)(SQ + base + c * 256) =
          make_float4(sqrtf(r0v[c * 4 + 0]), sqrtf(r0v[c * 4 + 1]),
                      sqrtf(r0v[c * 4 + 2]), sqrtf(r0v[c * 4 + 3]));
    }
    const float inv = 1.0f / wred_sum(sloc);
#pragma unroll
    for (int c = 0; c < 4; ++c) {
      float rn[4], a[4];
#pragma unroll
      for (int j = 0; j < 4; ++j) {
        rn[j] = r0v[c * 4 + j] * inv;
        const float s = softthr_full(rn[j]);
        a[j] = s * s;
      }
      *(float4*)(V + base + c * 256) = make_float4(rn[0], rn[1], rn[2], rn[3]);
      float* sp = &s_part[wv * NN + c * 256 + lane * 4];
      if (rr == 0) {
        *(float4*)sp = make_float4(a[0], a[1], a[2], a[3]);
      } else {
        float4 o = *(float4*)sp;
        *(float4*)sp = make_float4(o.x + a[0], o.y + a[1], o.z + a[2], o.w + a[3]);
      }
    }
  }
  __syncthreads();
  const int col = threadIdx.x * 4;
  const float4 s0 = *(float4*)(&s_part[0 * NN + col]);
  const float4 s1 = *(float4*)(&s_part[1 * NN + col]);
  const float4 s2 = *(float4*)(&s_part[2 * NN + col]);
  const float4 s3 = *(float4*)(&s_part[3 * NN + col]);
  float* dst = cs0 + (size_t)(blockIdx.x & (KSLOT - 1)) * NN + col;
  atomicAdd(dst + 0, (s0.x + s1.x) + (s2.x + s3.x));
  atomicAdd(dst + 1, (s0.y + s1.y) + (s2.y + s3.y));
  atomicAdd(dst + 2, (s0.z + s1.z) + (s2.z + s3.z));
  atomicAdd(dst + 3, (s0.w + s1.w) + (s2.w + s3.w));
}

__global__ __launch_bounds__(TPB) void k_ab(float* __restrict__ V,
                                            const float* __restrict__ SQ,
                                            const float* __restrict__ csPrev,
                                            float* __restrict__ csNext,
                                            int last) {
  __shared__ float s_scale[NN];
  __shared__ float s_part[WPB * NN];
  const int lane = threadIdx.x & 63;
  const int wv = threadIdx.x >> 6;
  {
    const int col = threadIdx.x * 4;
    float4 a = make_float4(0.f, 0.f, 0.f, 0.f);
#pragma unroll
    for (int k = 0; k < KSLOT; ++k) {
      const float4 v = *(const float4*)(csPrev + (size_t)k * NN + col);
      a.x += v.x; a.y += v.y; a.z += v.z; a.w += v.w;
    }
    s_scale[col + 0] = fmaxf(1.0f - SCLC / (sqrtf(a.x) + EPSL), 0.0f);
    s_scale[col + 1] = fmaxf(1.0f - SCLC / (sqrtf(a.y) + EPSL), 0.0f);
    s_scale[col + 2] = fmaxf(1.0f - SCLC / (sqrtf(a.z) + EPSL), 0.0f);
    s_scale[col + 3] = fmaxf(1.0f - SCLC / (sqrtf(a.w) + EPSL), 0.0f);
  }
  __syncthreads();

#pragma unroll
  for (int rr = 0; rr < FB_RPW; ++rr) {
    const size_t row = (size_t)blockIdx.x * FB_RPB + wv * FB_RPW + rr;
    const size_t base = row * NN + (size_t)lane * 4;
    float u[16], z[16];
    float sloc = 0.f;
#pragma unroll
    for (int c = 0; c < 4; ++c) {
      const float4 vv4 = *(const float4*)(V + base + c * 256);
      const float4 sq4 = *(const float4*)(SQ + base + c * 256);
      const float4 sc4 = *(const float4*)(&s_scale[c * 256 + lane * 4]);
      const float vv[4] = {vv4.x, vv4.y, vv4.z, vv4.w};
      const float sq[4] = {sq4.x, sq4.y, sq4.z, sq4.w};
      const float sc[4] = {sc4.x, sc4.y, sc4.z, sc4.w};
#pragma unroll
      for (int j = 0; j < 4; ++j) {
        const float s = softthr_full(vv[j]);
        const float X = sc[j] * s;
        const float zz = vv[j] - X;
        z[c * 4 + j] = zz;
        const float Xm = (X == 0.f) ? MINV : X;
        const float uu = sq[j] * sqrtf(Xm) * __expf(-0.5f * zz);
        u[c * 4 + j] = uu;
        sloc += uu;
      }
    }
    const float inv = 1.0f / wred_sum(sloc);
#pragma unroll
    for (int c = 0; c < 4; ++c) {
      float outv[4];
#pragma unroll
      for (int j = 0; j < 4; ++j) {
        const float rn = u[c * 4 + j] * inv;
        outv[j] = last ? rn : (rn + z[c * 4 + j]);
      }
      *(float4*)(V + base + c * 256) =
          make_float4(outv[0], outv[1], outv[2], outv[3]);
      if (!last) {
        float a[4];
#pragma unroll
        for (int j = 0; j < 4; ++j) {
          const float s = softthr_full(outv[j]);
          a[j] = s * s;
        }
        float* sp = &s_part[wv * NN + c * 256 + lane * 4];
        if (rr == 0) {
          *(float4*)sp = make_float4(a[0], a[1], a[2], a[3]);
        } else {
          float4 o = *(float4*)sp;
          *(float4*)sp =
              make_float4(o.x + a[0], o.y + a[1], o.z + a[2], o.w + a[3]);
        }
      }
    }
  }
  if (!last) {
    __syncthreads();
    const int col = threadIdx.x * 4;
    const float4 s0 = *(float4*)(&s_part[0 * NN + col]);
    const float4 s1 = *(float4*)(&s_part[1 * NN + col]);
    const float4 s2 = *(float4*)(&s_part[2 * NN + col]);
    const float4 s3 = *(float4*)(&s_part[3 * NN + col]);
    float* dst = csNext + (size_t)(blockIdx.x & (KSLOT - 1)) * NN + col;
    atomicAdd(dst + 0, (s0.x + s1.x) + (s2.x + s3.x));
    atomicAdd(dst + 1, (s0.y + s1.y) + (s2.y + s3.y));
    atomicAdd(dst + 2, (s0.z + s1.z) + (s2.z + s3.z));
    atomicAdd(dst + 3, (s0.w + s1.w) + (s2.w + s3.w));
  }
}

extern "C" void kernel_launch(void* const* d_in, const int* in_sizes, int n_in,
                              void* d_out, int out_size, void* d_ws, size_t ws_size,
                              hipStream_t stream) {
  (void)in_sizes; (void)n_in; (void)out_size; (void)ws_size;
  const float* R0 = (const float*)d_in[0];
  float* OUT = (float*)d_out;
  float* SQ = (float*)d_ws;   // 64 MB: used by fallback only
  float* cs = (float*)((char*)d_ws + (size_t)NROWS * NN * sizeof(float));
  unsigned* arr = (unsigned*)((char*)cs + CS_BYTES);       // counters
  unsigned* rel = arr + NARR * ARR_STRIDE + 64;            // own cacheline

  // Select by reading the COMPILED truth.
  //  C: scratch <= 256B (tiny spill OK at 8 blocks/CU) AND 2048 residency.
  //  B: proven ~802-us kernel, occupancy-gated.
  //  else: proven multi-kernel fallback.
  static int mode = -1;
  if (mode < 0) {
    mode = 0;
    int dev = 0, ncu = 0;
    if (hipGetDevice(&dev) == hipSuccess &&
        hipDeviceGetAttribute(&ncu, hipDeviceAttributeMultiprocessorCount,
                              dev) == hipSuccess) {
      hipFuncAttributes fc{};
      int maxb = 0;
      if (hipFuncGetAttributes(&fc, reinterpret_cast<const void*>(k_fc)) ==
              hipSuccess &&
          fc.localSizeBytes <= 256 &&
          hipOccupancyMaxActiveBlocksPerMultiprocessor(&maxb, k_fc, TPB, 0) ==
              hipSuccess &&
          (long)maxb * (long)ncu >= (long)C_NGRID) {
        mode = 3;
      } else if (hipFuncSetAttribute(
                     reinterpret_cast<const void*>(k_fb),
                     hipFuncAttributeMaxDynamicSharedMemorySize,
                     B_LDS_BYTES) == hipSuccess &&
                 hipOccupancyMaxActiveBlocksPerMultiprocessor(
                     &maxb, k_fb, TPB, B_LDS_BYTES) == hipSuccess &&
                 (long)maxb * (long)ncu >= (long)B_NGRID) {
        mode = 2;
      }
    }
  }

  // zero cs slices + arrival counters + release word
  hipMemsetAsync(cs, 0, CS_BYTES + 8192, stream);
  if (mode == 3) {
    k_fc<<<C_NGRID, TPB, 0, stream>>>(R0, OUT, cs, arr, rel);
  } else if (mode == 2) {
    k_fb<<<B_NGRID, TPB, B_LDS_BYTES, stream>>>(R0, OUT, cs, arr, rel);
  } else {
    k_start<<<FB_NGRID, TPB, 0, stream>>>(R0, OUT, SQ, cs);
    for (int it = 1; it < NIT; ++it) {
      k_ab<<<FB_NGRID, TPB, 0, stream>>>(OUT, SQ,
                                         cs + (size_t)(it - 1) * KSLOT * NN,
                                         cs + (size_t)it * KSLOT * NN,
                                         (it == NIT - 1) ? 1 : 0);
    }
  }
}